// Round 9
// baseline (1621.958 us; speedup 1.0000x reference)
//
#include <hip/hip_runtime.h>

// Volume (B=2, C=1, D=192, H=192, W=192) fp32 in/out.
// R9 = R8 algorithm (verified absmax 0.0039) with a WIDER per-block tile:
//   YPT 4->8 output rows per block (strip 14 rows: halo redundancy 2.5->1.75,
//   VALU/output -27%, barriers/output -50%), ZPT 8->12 (prologue 6/18=33%
//   of iterations, was 43%). NBLK=768. launch_bounds (192,3) caps VGPR ~170
//   (state ~145) -- no spill (R7 lesson; detect via FETCH/WRITE balloon).
//   All register arrays statically indexed (rule #20).
// Fused two-step kernel per launch: E1=erode(X), D1=dilate(E1),
// delta1=relu(X-D1), E2=erode(E1), D2=dilate(E2), delta2=relu(E1-D2),
// both skel updates; writes A_{j+2} and S only. Thread=x (coalesced),
// h2 pairs along y, single-buffered LDS x-halo (write->bar->read->bar,
// LDS-only barriers keep vmcnt prefetches in flight), z register pipeline
// (output z=p-3 when plane p loads).
//
// Slot ledger (y-slots relative to y0, pairs along y):
//   X a0: slots -2..9 (6 h2)   hm0 (y-min3 of X): -2..9 (6)
//   E1 e1: -2..9 (6)  trim t: -1..8 (5)  hm1: -1..8 (5)
//   E2 e2: -1..8 (5)  m1,m2,out: 0..7 (4)
// z-ages at iteration i (p=z0-3+i, output zo=p-3):
//   fresh: a(p), hm(p), E1(p-1), hm1(p-1), E2(p-2), m1(p-1), m2(p-2)
//   out zo: D1 from m1M3/m1M2/m1M1; D2 from m2M2/m2M1/m2_0;
//   X-center = xcM3 (a(p-3)[1..4]); E1-center from e1M2t; A-out = e2cM1.

#define Dn 192
#define Hn 192
#define Wn 192
#define PLANE (Hn * Wn)
#define TOTAL_ELEMS (2 * Dn * Hn * Wn)

// fused2 geometry
#define NYG2 (Hn / 8)          // 24 y-groups of 8 rows
#define ZPT2 12                // z planes per block
#define ZC2 (Dn / ZPT2)        // 16 z-chunks
#define NBLK2 (NYG2 * ZC2 * 2) // 768 blocks
#define NITER2 (ZPT2 + 6)      // 18 pipeline iterations

// single-step geometry (R8-verified, runs once)
#define NYG1 (Hn / 4)
#define ZPT1 8
#define ZC1 (Dn / ZPT1)
#define NBLK1 (NYG1 * ZC1 * 2) // 2304
#define NITER1 (ZPT1 + 4)

// LDS-only barrier: orders ds ops without draining global (vmcnt) prefetches.
static __device__ __forceinline__ void lds_barrier() {
    asm volatile("s_waitcnt lgkmcnt(0)" ::: "memory");
    __builtin_amdgcn_s_barrier();
}

typedef _Float16 h2 __attribute__((ext_vector_type(2)));
typedef _Float16 h4 __attribute__((ext_vector_type(4)));

static __device__ __forceinline__ h2 h2min(h2 a, h2 b) { return __builtin_elementwise_min(a, b); }
static __device__ __forceinline__ h2 h2max(h2 a, h2 b) { return __builtin_elementwise_max(a, b); }
static __device__ __forceinline__ h2 h2min3(h2 a, h2 b, h2 c) { return h2min(h2min(a, b), c); }
static __device__ __forceinline__ h2 h2max3(h2 a, h2 b, h2 c) { return h2max(h2max(a, b), c); }
static __device__ __forceinline__ unsigned int u32(h2 v) { return __builtin_bit_cast(unsigned int, v); }
static __device__ __forceinline__ h2 h2c(unsigned int v) { return __builtin_bit_cast(h2, v); }

template <int CHUNK>
__device__ __forceinline__ int swizzle(int bid) {
    return (bid & 7) * CHUNK + (bid >> 3);
}

// ---------------- fused two-step kernel (YPT=8, ZPT=12) ----------------
template <bool FIRST>
__global__ __launch_bounds__(192, 3) void fused2_k(const void* __restrict__ X_,
                                                   const _Float16* Sin,
                                                   _Float16* Sout,
                                                   _Float16* __restrict__ Aout) {
    const float* Xf = (const float*)X_;
    const _Float16* Xh = (const _Float16*)X_;

    const int bid = swizzle<NBLK2 / 8>((int)blockIdx.x);
    const int gy = bid % NYG2;
    const int t2 = bid / NYG2;
    const int zc = t2 % ZC2;
    const int b = t2 / ZC2;
    const int x = threadIdx.x;          // 0..191, contiguous across lanes
    const int y0 = gy * 8;
    const int z0 = zc * ZPT2;
    const int cbase = b * (Dn * PLANE) + y0 * Wn + x;

    // Clamped row offsets, rows y0-3 .. y0+10 (clamp = y-replicate boundary).
    int roff[14];
#pragma unroll
    for (int k = 0; k < 14; ++k) {
        int ry = y0 - 3 + k;
        ry = ry < 0 ? 0 : (ry > Hn - 1 ? Hn - 1 : ry);
        roff[k] = (ry - y0) * Wn;
    }

    // LDS (single-buffered): [x][0..5]=a0, [6..10]=t, [11..15]=e2.
    // Stride 17 (odd, coprime 32 banks -> 2 lanes/bank = free). 13.1 KB.
    __shared__ unsigned int sh[192][17];
    const int xu = (x < Wn - 1) ? x + 1 : x;
    const int xd = (x > 0) ? x - 1 : x;

    // z-pipeline state (zero-init; early consumers gated)
    h2 aM1[6] = {}, aM2[6] = {}, hmM1[6] = {}, aUM1[6] = {}, aDM1[6] = {};
    h2 e1M1t[5] = {}, e1M2t[5] = {}, hm1M1[5] = {}, e1UM1[5] = {}, e1DM1[5] = {};
    h2 m1M1[4] = {}, m1M2[4] = {}, m1M3[4] = {};
    h2 m2M1[4] = {}, m2M2[4] = {};
    h2 xcM3[4] = {};            // X center at output plane (a(p-3)[1..4])
    h2 e2cM1[4] = {};
    h4 sPa = {}, sPb = {};      // skel prefetch, rows 0..3 / 4..7

    _Float16 hP[14];
    float fP[14];
    auto issue = [&](int p) {
        int pz = p < 0 ? 0 : (p > Dn - 1 ? Dn - 1 : p);  // z-clamp (neutral)
        if (FIRST) {
            const float* pp = Xf + cbase + pz * PLANE;
#pragma unroll
            for (int k = 0; k < 14; ++k) fP[k] = pp[roff[k]];
        } else {
            const _Float16* pp = Xh + cbase + pz * PLANE;
#pragma unroll
            for (int k = 0; k < 14; ++k) hP[k] = pp[roff[k]];
        }
    };
    issue(z0 - 3);

#pragma unroll
    for (int i = 0; i < NITER2; ++i) {
        const int p = z0 - 3 + i;
        const int zo = p - 3;

        // ---- strip: 14 y-values [y0-3..y0+10] at (x, plane p)
        _Float16 s[14];
#pragma unroll
        for (int k = 0; k < 14; ++k) s[k] = FIRST ? (_Float16)fP[k] : hP[k];

        if (i + 1 < NITER2) issue(p + 1);

        // skel prefetch for NEXT iteration's output (plane p-2)
        h4 sNa = {}, sNb = {};
        if (!FIRST && i >= 5 && i + 1 < NITER2) {
            const _Float16* sp = Sin + cbase + (p - 2) * PLANE;
            sNa.x = sp[0];      sNa.y = sp[Wn];
            sNa.z = sp[2 * Wn]; sNa.w = sp[3 * Wn];
            sNb.x = sp[4 * Wn]; sNb.y = sp[5 * Wn];
            sNb.z = sp[6 * Wn]; sNb.w = sp[7 * Wn];
        }

        // ---- per-plane X summaries
        h2 P[13];
#pragma unroll
        for (int k = 0; k < 13; ++k) { h2 t_ = {s[k], s[k + 1]}; P[k] = t_; }
        h2 a0[6] = {P[1], P[3], P[5], P[7], P[9], P[11]};   // slots -2..9
        h2 hm0[6];
#pragma unroll
        for (int j = 0; j < 6; ++j)
            hm0[j] = h2min3(P[2 * j], P[2 * j + 1], P[2 * j + 2]);  // y-min3

        // ---- E1(p-1) slots -2..9 ; trim t slots -1..8 ; hm1(p-1)
        h2 e1[6] = {}, t[5] = {}, hm1_0[5] = {};
        if (i >= 2) {
#pragma unroll
            for (int k = 0; k < 6; ++k)
                e1[k] = h2min3(h2min(hmM1[k], aM2[k]),
                               h2min(aUM1[k], aDM1[k]), a0[k]);
            if (gy == 0)        { h2 v = {e1[1].x, e1[1].x}; e1[0] = v; }
            if (gy == NYG2 - 1) { h2 v = {e1[4].y, e1[4].y}; e1[5] = v; }
#pragma unroll
            for (int j = 0; j < 5; ++j)
                t[j] = __builtin_shufflevector(e1[j], e1[j + 1], 1, 2);
#pragma unroll
            for (int j = 0; j < 5; ++j)
                hm1_0[j] = h2min3(e1[j], t[j], e1[j + 1]);
        }

        // ---- E2(p-2) slots -1..8 ; e2c(p-2) output slots 0..7
        h2 e2[5] = {}, e2c0[4] = {};
        if (i >= 4) {
#pragma unroll
            for (int j = 0; j < 5; ++j)
                e2[j] = h2min3(h2min(hm1M1[j], e1M2t[j]),
                               h2min(e1UM1[j], e1DM1[j]), t[j]);
            if (gy == 0)        { h2 v = {e2[0].y, e2[0].y}; e2[0] = v; }
            if (gy == NYG2 - 1) { h2 v = {e2[4].x, e2[4].x}; e2[4] = v; }
#pragma unroll
            for (int q = 0; q < 4; ++q)
                e2c0[q] = __builtin_shufflevector(e2[q], e2[q + 1], 1, 2);
        }

        // ---- LDS exchange: write -> bar -> read -> bar (single buffer)
#pragma unroll
        for (int k = 0; k < 6; ++k) sh[x][k] = u32(a0[k]);
        if (i >= 2) {
#pragma unroll
            for (int j = 0; j < 5; ++j) sh[x][6 + j] = u32(t[j]);
        }
        if (i >= 4) {
#pragma unroll
            for (int j = 0; j < 5; ++j) sh[x][11 + j] = u32(e2[j]);
        }
        lds_barrier();
        h2 aU0[6], aD0[6];
#pragma unroll
        for (int k = 0; k < 6; ++k) {
            aU0[k] = h2c(sh[xu][k]);
            aD0[k] = h2c(sh[xd][k]);
        }
        h2 tU[5] = {}, tD[5] = {}, eUr[5] = {}, eDr[5] = {};
        if (i >= 2) {
#pragma unroll
            for (int j = 0; j < 5; ++j) {
                tU[j] = h2c(sh[xu][6 + j]);
                tD[j] = h2c(sh[xd][6 + j]);
            }
        }
        if (i >= 4) {
#pragma unroll
            for (int j = 0; j < 5; ++j) {
                eUr[j] = h2c(sh[xu][11 + j]);
                eDr[j] = h2c(sh[xd][11 + j]);
            }
        }
        lds_barrier();

        // ---- m1(p-1) / m2(p-2): in-plane 3x3 max, output slots 0..7
        h2 m1_0[4] = {}, m2_0[4] = {};
        if (i >= 2) {
            h2 vm[5];
#pragma unroll
            for (int j = 0; j < 5; ++j) vm[j] = h2max3(t[j], tU[j], tD[j]);
#pragma unroll
            for (int q = 0; q < 4; ++q) {
                h2 mid = __builtin_shufflevector(vm[q], vm[q + 1], 1, 2);
                m1_0[q] = h2max3(vm[q], mid, vm[q + 1]);
            }
        }
        if (i >= 4) {
            h2 wm[5];
#pragma unroll
            for (int j = 0; j < 5; ++j) wm[j] = h2max3(e2[j], eUr[j], eDr[j]);
#pragma unroll
            for (int q = 0; q < 4; ++q) {
                h2 mid = __builtin_shufflevector(wm[q], wm[q + 1], 1, 2);
                m2_0[q] = h2max3(wm[q], mid, wm[q + 1]);
            }
        }

        // ---- output z = p-3 (8 rows)
        if (i >= 6) {
            const int offo = cbase + zo * PLANE;
            const bool zlo = (zo == 0);
            const bool zhi = (zo == Dn - 1);
            float sv[8];
            sv[0] = (float)sPa.x; sv[1] = (float)sPa.y;
            sv[2] = (float)sPa.z; sv[3] = (float)sPa.w;
            sv[4] = (float)sPb.x; sv[5] = (float)sPb.y;
            sv[6] = (float)sPb.z; sv[7] = (float)sPb.w;
#pragma unroll
            for (int q = 0; q < 4; ++q) {
                h2 d1a = zlo ? m1M2[q] : m1M3[q];
                h2 d1c = zhi ? m1M2[q] : m1M1[q];
                h2 D1 = h2max3(d1a, m1M2[q], d1c);
                h2 d2a = zlo ? m2M1[q] : m2M2[q];
                h2 d2c = zhi ? m2M1[q] : m2_0[q];
                h2 D2 = h2max3(d2a, m2M1[q], d2c);
                h2 e1cz = __builtin_shufflevector(e1M2t[q], e1M2t[q + 1], 1, 2);
                float ex0 = (float)xcM3[q].x, ex1 = (float)xcM3[q].y;
                float e10 = (float)e1cz.x,   e11 = (float)e1cz.y;
                float dA0 = (float)D1.x,     dA1 = (float)D1.y;
                float dB0 = (float)D2.x,     dB1 = (float)D2.y;
                float de1a = fmaxf(ex0 - dA0, 0.f);
                float de1b = fmaxf(ex1 - dA1, 0.f);
                float s1a = FIRST ? de1a
                                  : (sv[2 * q] + fmaxf(de1a - sv[2 * q] * de1a, 0.f));
                float s1b = FIRST ? de1b
                                  : (sv[2 * q + 1] + fmaxf(de1b - sv[2 * q + 1] * de1b, 0.f));
                float de2a = fmaxf(e10 - dB0, 0.f);
                float de2b = fmaxf(e11 - dB1, 0.f);
                sv[2 * q] = s1a + fmaxf(de2a - s1a * de2a, 0.f);
                sv[2 * q + 1] = s1b + fmaxf(de2b - s1b * de2b, 0.f);
            }
#pragma unroll
            for (int r = 0; r < 8; ++r)
                Sout[offo + r * Wn] = (_Float16)sv[r];
            Aout[offo]          = e2cM1[0].x;
            Aout[offo + Wn]     = e2cM1[0].y;
            Aout[offo + 2 * Wn] = e2cM1[1].x;
            Aout[offo + 3 * Wn] = e2cM1[1].y;
            Aout[offo + 4 * Wn] = e2cM1[2].x;
            Aout[offo + 5 * Wn] = e2cM1[2].y;
            Aout[offo + 6 * Wn] = e2cM1[3].x;
            Aout[offo + 7 * Wn] = e2cM1[3].y;
        }

        // ---- rotate pipeline state (xcM3 from OLD aM2 before overwrite)
        xcM3[0] = aM2[1]; xcM3[1] = aM2[2]; xcM3[2] = aM2[3]; xcM3[3] = aM2[4];
#pragma unroll
        for (int k = 0; k < 6; ++k) {
            aM2[k] = aM1[k]; aM1[k] = a0[k];
            hmM1[k] = hm0[k]; aUM1[k] = aU0[k]; aDM1[k] = aD0[k];
        }
#pragma unroll
        for (int j = 0; j < 5; ++j) {
            e1M2t[j] = e1M1t[j]; e1M1t[j] = t[j];
            hm1M1[j] = hm1_0[j]; e1UM1[j] = tU[j]; e1DM1[j] = tD[j];
        }
#pragma unroll
        for (int q = 0; q < 4; ++q) {
            m1M3[q] = m1M2[q]; m1M2[q] = m1M1[q]; m1M1[q] = m1_0[q];
            m2M2[q] = m2M1[q]; m2M1[q] = m2_0[q];
            e2cM1[q] = e2c0[q];
        }
        sPa = sNa; sPb = sNb;
    }
}

// ---------------- single-step kernel (R8-verified, runs once) ----------
template <bool FIRST, bool LAST>
__global__ __launch_bounds__(192, 4) void step_k(const void* __restrict__ X_,
                                                 const _Float16* Sin,
                                                 void* Sout_,
                                                 _Float16* __restrict__ Aout) {
    const float* Xf = (const float*)X_;
    const _Float16* Xh = (const _Float16*)X_;
    _Float16* Sh = (_Float16*)Sout_;
    float* Sf = (float*)Sout_;

    const int bid = swizzle<NBLK1 / 8>((int)blockIdx.x);
    const int gy = bid % NYG1;
    const int t2 = bid / NYG1;
    const int zc = t2 % ZC1;
    const int b = t2 / ZC1;
    const int x = threadIdx.x;
    const int y0 = gy * 4;
    const int z0 = zc * ZPT1;
    const int cbase = b * (Dn * PLANE) + y0 * Wn + x;

    int roff[8];
#pragma unroll
    for (int k = 0; k < 8; ++k) {
        int ry = y0 - 2 + k;
        ry = ry < 0 ? 0 : (ry > Hn - 1 ? Hn - 1 : ry);
        roff[k] = (ry - y0) * Wn;
    }

    __shared__ unsigned int sh[192][7];
    const int xu = (x < Wn - 1) ? x + 1 : x;
    const int xd = (x > 0) ? x - 1 : x;

    h2 aM2[3] = {}, aM1[3] = {}, hmM1[3] = {}, aUM1[3] = {}, aDM1[3] = {};
    h2 xcM1[2] = {}, xcM2[2] = {}, e1cM1[2] = {}, mM1[2] = {}, mM2[2] = {};

    _Float16 hP[8];
    float fP[8];
    h4 sP = {};

    auto issue = [&](int p) {
        int pz = p < 0 ? 0 : (p > Dn - 1 ? Dn - 1 : p);
        if (FIRST) {
            const float* pp = Xf + cbase + pz * PLANE;
#pragma unroll
            for (int k = 0; k < 8; ++k) fP[k] = pp[roff[k]];
        } else {
            const _Float16* pp = Xh + cbase + pz * PLANE;
#pragma unroll
            for (int k = 0; k < 8; ++k) hP[k] = pp[roff[k]];
        }
    };
    issue(z0 - 2);

#pragma unroll
    for (int i = 0; i < NITER1; ++i) {
        const int p = z0 - 2 + i;
        const int zo = p - 2;

        _Float16 s[8];
#pragma unroll
        for (int k = 0; k < 8; ++k) s[k] = FIRST ? (_Float16)fP[k] : hP[k];

        if (i + 1 < NITER1) issue(p + 1);

        h4 sN = {};
        if (!FIRST && i >= 3 && i + 1 < NITER1) {
            const _Float16* sp = Sin + cbase + (p - 1) * PLANE;
            sN.x = sp[0]; sN.y = sp[Wn]; sN.z = sp[2 * Wn]; sN.w = sp[3 * Wn];
        }

        h2 P[7];
#pragma unroll
        for (int k = 0; k < 7; ++k) { h2 t = {s[k], s[k + 1]}; P[k] = t; }
        h2 a0[3] = {P[1], P[3], P[5]};
        h2 hm0[3];
#pragma unroll
        for (int j = 0; j < 3; ++j)
            hm0[j] = h2min3(P[2 * j], P[2 * j + 1], P[2 * j + 2]);
        h2 xc0[2] = {P[2], P[4]};

        h2 e1[3] = {};
        if (i >= 2) {
#pragma unroll
            for (int k = 0; k < 3; ++k)
                e1[k] = h2min3(h2min(hmM1[k], aM2[k]),
                               h2min(aUM1[k], aDM1[k]), a0[k]);
            if (gy == 0)        e1[0] = __builtin_shufflevector(e1[0], e1[0], 1, 1);
            if (gy == NYG1 - 1) e1[2] = __builtin_shufflevector(e1[2], e1[2], 0, 0);
        }

        sh[x][0] = u32(a0[0]);
        sh[x][1] = u32(a0[1]);
        sh[x][2] = u32(a0[2]);
        if (i >= 2) {
            sh[x][3] = u32(e1[0]);
            sh[x][4] = u32(e1[1]);
            sh[x][5] = u32(e1[2]);
        }
        lds_barrier();
        h2 aU0[3] = {h2c(sh[xu][0]), h2c(sh[xu][1]), h2c(sh[xu][2])};
        h2 aD0[3] = {h2c(sh[xd][0]), h2c(sh[xd][1]), h2c(sh[xd][2])};
        h2 eU0 = {}, eU1 = {}, eU2 = {}, eD0 = {}, eD1 = {}, eD2 = {};
        if (i >= 2) {
            eU0 = h2c(sh[xu][3]); eU1 = h2c(sh[xu][4]); eU2 = h2c(sh[xu][5]);
            eD0 = h2c(sh[xd][3]); eD1 = h2c(sh[xd][4]); eD2 = h2c(sh[xd][5]);
        }
        lds_barrier();

        h2 m0[2] = {}, e1c0[2] = {};
        if (i >= 2) {
            h2 vm0 = h2max3(e1[0], eU0, eD0);
            h2 vm1 = h2max3(e1[1], eU1, eD1);
            h2 vm2 = h2max3(e1[2], eU2, eD2);
            h2 mid01 = __builtin_shufflevector(vm0, vm1, 1, 2);
            h2 mid23 = __builtin_shufflevector(vm1, vm2, 1, 2);
            m0[0] = h2max3(vm0, mid01, vm1);
            m0[1] = h2max3(vm1, mid23, vm2);
            e1c0[0] = __builtin_shufflevector(e1[0], e1[1], 1, 2);
            e1c0[1] = __builtin_shufflevector(e1[1], e1[2], 1, 2);
        }

        if (i >= 4) {
            const int offo = cbase + zo * PLANE;
            const bool zlo = (zo == 0);
            const bool zhi = (zo == Dn - 1);
            h2 mzA0 = zlo ? mM1[0] : mM2[0];
            h2 mzA1 = zlo ? mM1[1] : mM2[1];
            h2 mzC0 = zhi ? mM1[0] : m0[0];
            h2 mzC1 = zhi ? mM1[1] : m0[1];
            h2 d01 = h2max3(mzA0, mM1[0], mzC0);
            h2 d23 = h2max3(mzA1, mM1[1], mzC1);

            float ex0 = (float)xcM2[0].x, ex1 = (float)xcM2[0].y;
            float ex2 = (float)xcM2[1].x, ex3 = (float)xcM2[1].y;
            float de0 = fmaxf(ex0 - (float)d01.x, 0.f);
            float de1 = fmaxf(ex1 - (float)d01.y, 0.f);
            float de2 = fmaxf(ex2 - (float)d23.x, 0.f);
            float de3 = fmaxf(ex3 - (float)d23.y, 0.f);
            float s0, s1, s2, s3;
            if (FIRST) {
                s0 = de0; s1 = de1; s2 = de2; s3 = de3;
            } else {
                s0 = (float)sP.x; s1 = (float)sP.y;
                s2 = (float)sP.z; s3 = (float)sP.w;
                s0 += fmaxf(de0 - s0 * de0, 0.f);
                s1 += fmaxf(de1 - s1 * de1, 0.f);
                s2 += fmaxf(de2 - s2 * de2, 0.f);
                s3 += fmaxf(de3 - s3 * de3, 0.f);
            }
            if (LAST) {
                Sf[offo] = s0; Sf[offo + Wn] = s1;
                Sf[offo + 2 * Wn] = s2; Sf[offo + 3 * Wn] = s3;
            } else {
                Sh[offo] = (_Float16)s0;
                Sh[offo + Wn] = (_Float16)s1;
                Sh[offo + 2 * Wn] = (_Float16)s2;
                Sh[offo + 3 * Wn] = (_Float16)s3;
                Aout[offo] = e1cM1[0].x;
                Aout[offo + Wn] = e1cM1[0].y;
                Aout[offo + 2 * Wn] = e1cM1[1].x;
                Aout[offo + 3 * Wn] = e1cM1[1].y;
            }
        }

#pragma unroll
        for (int k = 0; k < 3; ++k) {
            aM2[k] = aM1[k]; aM1[k] = a0[k];
            hmM1[k] = hm0[k]; aUM1[k] = aU0[k]; aDM1[k] = aD0[k];
        }
        xcM2[0] = xcM1[0]; xcM2[1] = xcM1[1];
        xcM1[0] = xc0[0];  xcM1[1] = xc0[1];
        if (i >= 2) {
            mM2[0] = mM1[0]; mM2[1] = mM1[1];
            mM1[0] = m0[0];  mM1[1] = m0[1];
            e1cM1[0] = e1c0[0]; e1cM1[1] = e1c0[1];
        }
        sP = sN;
    }
}

extern "C" void kernel_launch(void* const* d_in, const int* in_sizes, int n_in,
                              void* d_out, int out_size, void* d_ws, size_t ws_size,
                              hipStream_t stream) {
    const float* img = (const float*)d_in[0];
    _Float16* B0 = (_Float16*)d_ws;
    _Float16* B1 = B0 + TOTAL_ELEMS;
    _Float16* S  = B1 + TOTAL_ELEMS;   // 3 x 28.3 MB workspace (fp16)

    // 41 opening steps: fused pair (0,1) from fp32 img, 19 fused pairs
    // (2,3)..(38,39), single final step 40 writing fp32 to d_out.
    fused2_k<true><<<NBLK2, 192, 0, stream>>>(img, nullptr, S, B0);  // -> A_2
    _Float16* a = B0;
    _Float16* nb = B1;
    for (int j = 0; j < 19; ++j) {
        fused2_k<false><<<NBLK2, 192, 0, stream>>>(a, S, S, nb);
        _Float16* t = a; a = nb; nb = t;                              // -> A_40
    }
    step_k<false, true><<<NBLK1, 192, 0, stream>>>(a, S, d_out, nullptr);
}